// Round 6
// baseline (177.176 us; speedup 1.0000x reference)
//
#include <hip/hip_runtime.h>
#include <hip/hip_bf16.h>

#define NB 4
#define NC 256
#define NN 4096
#define NCR 32

typedef __attribute__((ext_vector_type(8))) short short8_t;
typedef __attribute__((ext_vector_type(4))) float f32x4;
typedef __attribute__((ext_vector_type(16))) float f32x16;
typedef __attribute__((ext_vector_type(2))) int int2_t;
typedef __attribute__((ext_vector_type(4))) int int4_t;
typedef __attribute__((ext_vector_type(4))) float float4_t;

static __device__ __forceinline__ unsigned short f2bf(float f) {
  unsigned u = __builtin_bit_cast(unsigned, f);
  u += 0x7FFFu + ((u >> 16) & 1u);
  return (unsigned short)(u >> 16);
}

static __device__ __forceinline__ unsigned cvt_pk(float lo, float hi) {
  unsigned r;
  asm("v_cvt_pk_bf16_f32 %0, %1, %2" : "=v"(r) : "v"(lo), "v"(hi));
  return r;
}

// ---------------------------------------------------------------------------
// Kernel 0: one-time W pack f32 -> bf16. rows [0,32)=Wq, [32,64)=Wk, [64,320)=Wv
// ---------------------------------------------------------------------------
__global__ __launch_bounds__(64) void pack_w_kernel(
    const float* __restrict__ Wq, const float* __restrict__ Wk,
    const float* __restrict__ Wv, unsigned short* __restrict__ Wbf)
{
  const int row = blockIdx.x;
  const int t = threadIdx.x;
  const float* src = row < 32 ? Wq + (size_t)row * NC
                   : (row < 64 ? Wk + (size_t)(row - 32) * NC
                               : Wv + (size_t)(row - 64) * NC);
  float4_t v = *(const float4_t*)(src + t * 4);
  int2_t p;
  p[0] = cvt_pk(v[0], v[1]);
  p[1] = cvt_pk(v[2], v[3]);
  *(int2_t*)(Wbf + (size_t)row * NC + t * 4) = p;
}

// ---------------------------------------------------------------------------
// Kernel 0b: transpose+cast x[b][k][m] f32 -> xT[b][m][k] bf16.
// ---------------------------------------------------------------------------
__global__ __launch_bounds__(256) void xpose_kernel(
    const float* __restrict__ x, unsigned short* __restrict__ xT)
{
  __shared__ float tile[32][65];
  const int bid = blockIdx.x;
  const int mt = bid & 63, kt = (bid >> 6) & 7, b = bid >> 9;
  const int m0 = mt * 64, k0 = kt * 32;
  const int tid = threadIdx.x;

  const float* xb = x + (size_t)b * NC * NN + (size_t)k0 * NN + m0;
#pragma unroll
  for (int p = 0; p < 8; p++) {
    const int r = p * 4 + (tid >> 6);
    tile[r][tid & 63] = xb[(size_t)r * NN + (tid & 63)];
  }
  __syncthreads();

  const int m = tid >> 2, kq = (tid & 3) * 8;
  int4_t o;
#pragma unroll
  for (int j = 0; j < 4; j++)
    o[j] = cvt_pk(tile[kq + 2 * j][m], tile[kq + 2 * j + 1][m]);
  *(int4_t*)(xT + ((size_t)b * NN + m0 + m) * NC + k0 + kq) = o;
}

// ---------------------------------------------------------------------------
// Kernel 1: QKV projection — pure streaming GEMM, no LDS.
// ---------------------------------------------------------------------------
__global__ __launch_bounds__(256, 2) void qkv_kernel(
    const unsigned short* __restrict__ xT, const unsigned short* __restrict__ Wbf,
    const float* __restrict__ bq, const float* __restrict__ bk,
    const float* __restrict__ bv,
    unsigned short* __restrict__ Qt, unsigned short* __restrict__ Kt,
    unsigned short* __restrict__ Vt)
{
  const int bid = blockIdx.x;
  const int b   = bid >> 7;
  const int m0  = (bid & 127) * 32;
  const int tid = threadIdx.x;
  const int w    = tid >> 6;
  const int lane = tid & 63;
  const int lg   = lane >> 4;
  const int lm   = lane & 15;

  const unsigned short* xrow0 = xT + ((size_t)b * NN + m0 + lm) * NC + lg * 8;
  const unsigned short* xrow1 = xrow0 + 16 * NC;
  const unsigned short* wrow  = Wbf + (size_t)(w * 80 + lm) * NC + lg * 8;

  const f32x4 zero4 = {0.f, 0.f, 0.f, 0.f};
  f32x4 acc[5][2];
#pragma unroll
  for (int df = 0; df < 5; df++)
#pragma unroll
    for (int mf = 0; mf < 2; mf++) acc[df][mf] = zero4;

#pragma unroll
  for (int kc = 0; kc < 8; kc++) {
    const short8_t xf0 = *(const short8_t*)(xrow0 + kc * 32);
    const short8_t xf1 = *(const short8_t*)(xrow1 + kc * 32);
#pragma unroll
    for (int df = 0; df < 5; df++) {
      const short8_t wf = *(const short8_t*)(wrow + (size_t)df * 16 * NC + kc * 32);
      acc[df][0] = __builtin_amdgcn_mfma_f32_16x16x32_bf16(xf0, wf, acc[df][0], 0, 0, 0);
      acc[df][1] = __builtin_amdgcn_mfma_f32_16x16x32_bf16(xf1, wf, acc[df][1], 0, 0, 0);
    }
  }

#pragma unroll
  for (int df = 0; df < 5; df++) {
    const int dbase = w * 80 + df * 16;
    if (dbase < 64) {
      const bool isq = dbase < 32;
      const float bia = isq ? bq[dbase + lm] : bk[dbase - 32 + lm];
      unsigned short* dst = isq ? Qt : Kt;
      const int dcol = (isq ? dbase : dbase - 32) + lm;
#pragma unroll
      for (int mf = 0; mf < 2; mf++)
#pragma unroll
        for (int i = 0; i < 4; i++) {
          const int m = m0 + mf * 16 + lg * 4 + i;
          dst[((size_t)b * NN + m) * NCR + dcol] = f2bf(acc[df][mf][i] + bia);
        }
    } else {
      const int c = dbase - 64 + lm;
      const float bia = bv[c];
#pragma unroll
      for (int mf = 0; mf < 2; mf++) {
        int2_t p;
        p[0] = cvt_pk(acc[df][mf][0] + bia, acc[df][mf][1] + bia);
        p[1] = cvt_pk(acc[df][mf][2] + bia, acc[df][mf][3] + bia);
        *(int2_t*)(Vt + ((size_t)b * NC + c) * NN + m0 + mf * 16 + lg * 4) = p;
      }
    }
  }
}

// ---------------------------------------------------------------------------
// Kernel 2: barrier-free streaming attention. 32x32x16 MFMAs; S stays in
// registers; P redistributed lane-locally via cvt_pk + permlane32_swap (T12).
// Wave = (m32, c64-shared, all n). Block = 4 waves (same c-range, m128 tile,
// shared K/V lines -> L1 dedup). No LDS, no __syncthreads.
// Grid 512 = XCD(8: b x cr-half) x [cr-lo, mt(32)].
// ---------------------------------------------------------------------------
__global__ __launch_bounds__(256, 2) void attn_kernel(
    const unsigned short* __restrict__ Qt, const unsigned short* __restrict__ Kt,
    const unsigned short* __restrict__ Vt, const float* __restrict__ x,
    const float* __restrict__ gamma, float* __restrict__ out)
{
  const int bid = blockIdx.x;
  const int xcd = bid & 7;
  const int idx = bid >> 3;                    // 0..63
  const int b   = xcd >> 1;                    // batch per XCD pair
  const int cr  = (xcd & 1) * 2 + (idx & 1);   // c-range 0..3 (64 rows each)
  const int mt  = idx >> 1;                    // 0..31 (m-tile of 128)
  const int tid = threadIdx.x;
  const int w    = tid >> 6;
  const int lane = tid & 63;
  const int l31  = lane & 31;
  const int h    = lane >> 5;

  const int m0    = mt * 128 + w * 32;
  const int cbase = cr * 64;

  const unsigned short* Qb = Qt + (size_t)b * NN * NCR;
  const unsigned short* Kp = Kt + (size_t)b * NN * NCR + (size_t)l31 * NCR + h * 8;
  const unsigned short* Vp0 = Vt + ((size_t)b * NC + cbase + l31) * NN + h * 8;
  const unsigned short* Vp1 = Vp0 + (size_t)32 * NN;

  // Q B-frags (whole kernel): col m = l31, k = ks*16 + 8h + i
  const short8_t qf0 = *(const short8_t*)(Qb + (size_t)(m0 + l31) * NCR + h * 8);
  const short8_t qf1 = *(const short8_t*)(Qb + (size_t)(m0 + l31) * NCR + 16 + h * 8);

  f32x16 accA, accB, zero16;
#pragma unroll
  for (int i = 0; i < 16; i++) { accA[i] = 0.f; accB[i] = 0.f; zero16[i] = 0.f; }
  float dsum = 0.f;

  // prologue: tile 0 K/V fragments
  short8_t kA[2], kB[2], vA[2][2], vB[2][2];
  kA[0] = *(const short8_t*)(Kp);
  kA[1] = *(const short8_t*)(Kp + 16);
  vA[0][0] = *(const short8_t*)(Vp0);
  vA[0][1] = *(const short8_t*)(Vp0 + 16);
  vA[1][0] = *(const short8_t*)(Vp1);
  vA[1][1] = *(const short8_t*)(Vp1 + 16);

#define AITER(T, KC, KN, VC, VN) {                                            \
    const int n1 = (((T) + 1) & 127) * 32;                                    \
    KN[0] = *(const short8_t*)(Kp + (size_t)n1 * NCR);                        \
    KN[1] = *(const short8_t*)(Kp + (size_t)n1 * NCR + 16);                   \
    VN[0][0] = *(const short8_t*)(Vp0 + n1);                                  \
    VN[0][1] = *(const short8_t*)(Vp0 + n1 + 16);                             \
    VN[1][0] = *(const short8_t*)(Vp1 + n1);                                  \
    VN[1][1] = *(const short8_t*)(Vp1 + n1 + 16);                             \
    /* S = K.Q : col m = l31, row n = (r&3)+8*(r>>2)+4h */                    \
    f32x16 s = __builtin_amdgcn_mfma_f32_32x32x16_bf16(KC[0], qf0, zero16, 0, 0, 0); \
    s = __builtin_amdgcn_mfma_f32_32x32x16_bf16(KC[1], qf1, s, 0, 0, 0);      \
    float r_[16];                                                             \
    _Pragma("unroll") for (int i = 0; i < 16; i++) r_[i] = fmaxf(s[i], 0.f);  \
    dsum += (((r_[0] + r_[1]) + (r_[2] + r_[3])) +                            \
             ((r_[4] + r_[5]) + (r_[6] + r_[7]))) +                           \
            (((r_[8] + r_[9]) + (r_[10] + r_[11])) +                          \
             ((r_[12] + r_[13]) + (r_[14] + r_[15])));                        \
    unsigned p0 = cvt_pk(r_[0], r_[1]), p1 = cvt_pk(r_[2], r_[3]);            \
    unsigned p2 = cvt_pk(r_[4], r_[5]), p3 = cvt_pk(r_[6], r_[7]);            \
    unsigned p4 = cvt_pk(r_[8], r_[9]), p5 = cvt_pk(r_[10], r_[11]);          \
    unsigned p6 = cvt_pk(r_[12], r_[13]), p7 = cvt_pk(r_[14], r_[15]);        \
    asm("v_permlane32_swap_b32 %0, %1" : "+v"(p0), "+v"(p2));                 \
    asm("v_permlane32_swap_b32 %0, %1" : "+v"(p1), "+v"(p3));                 \
    asm("v_permlane32_swap_b32 %0, %1" : "+v"(p4), "+v"(p6));                 \
    asm("v_permlane32_swap_b32 %0, %1" : "+v"(p5), "+v"(p7));                 \
    int4_t pb0i = {(int)p0, (int)p1, (int)p2, (int)p3};                       \
    int4_t pb1i = {(int)p4, (int)p5, (int)p6, (int)p7};                       \
    const short8_t pb0 = __builtin_bit_cast(short8_t, pb0i);                  \
    const short8_t pb1 = __builtin_bit_cast(short8_t, pb1i);                  \
    __builtin_amdgcn_s_setprio(1);                                            \
    accA = __builtin_amdgcn_mfma_f32_32x32x16_bf16(VC[0][0], pb0, accA, 0, 0, 0); \
    accA = __builtin_amdgcn_mfma_f32_32x32x16_bf16(VC[0][1], pb1, accA, 0, 0, 0); \
    accB = __builtin_amdgcn_mfma_f32_32x32x16_bf16(VC[1][0], pb0, accB, 0, 0, 0); \
    accB = __builtin_amdgcn_mfma_f32_32x32x16_bf16(VC[1][1], pb1, accB, 0, 0, 0); \
    __builtin_amdgcn_s_setprio(0);                                            \
  }

#pragma unroll 1
  for (int t = 0; t < 128; t += 2) {
    AITER(t, kA, kB, vA, vB)
    AITER(t + 1, kB, kA, vB, vA)
  }
#undef AITER

  // denominator: halves exchange (rows 4h offsets) -> full sum per m = l31
  dsum += __shfl_xor(dsum, 32);
  const float rden = 1.0f / (dsum > 1e-12f ? dsum : 1e-12f);
  const float g0 = gamma[0];

  const int m = m0 + l31;
  const float* xb = x + (size_t)b * NC * NN + m;
  float* ob = out + (size_t)b * NC * NN + m;
#pragma unroll
  for (int r = 0; r < 16; r++) {
    const int c0 = cbase + (r & 3) + 8 * (r >> 2) + 4 * h;
    ob[(size_t)c0 * NN] = g0 * accA[r] * rden + xb[(size_t)c0 * NN];
    const int c1 = c0 + 32;
    ob[(size_t)c1 * NN] = g0 * accB[r] * rden + xb[(size_t)c1 * NN];
  }
}

extern "C" void kernel_launch(void* const* d_in, const int* in_sizes, int n_in,
                              void* d_out, int out_size, void* d_ws, size_t ws_size,
                              hipStream_t stream) {
  const float* x     = (const float*)d_in[0];
  const float* Wq    = (const float*)d_in[1];
  const float* bq    = (const float*)d_in[2];
  const float* Wk    = (const float*)d_in[3];
  const float* bk    = (const float*)d_in[4];
  const float* Wv    = (const float*)d_in[5];
  const float* bv    = (const float*)d_in[6];
  const float* gamma = (const float*)d_in[7];
  float* out = (float*)d_out;

  // ws (bf16): Wbf[320][256], xT[4][4096][256], Qt[4][4096][32], Kt[..], Vt[4][256][4096]
  unsigned short* Wbf = (unsigned short*)d_ws;
  unsigned short* xT  = Wbf + (size_t)320 * NC;
  unsigned short* Qt  = xT + (size_t)NB * NN * NC;
  unsigned short* Kt  = Qt + (size_t)NB * NN * NCR;
  unsigned short* Vt  = Kt + (size_t)NB * NN * NCR;

  hipLaunchKernelGGL(pack_w_kernel, dim3(320), dim3(64), 0, stream,
                     Wq, Wk, Wv, Wbf);
  hipLaunchKernelGGL(xpose_kernel, dim3(2048), dim3(256), 0, stream, x, xT);
  hipLaunchKernelGGL(qkv_kernel, dim3(512), dim3(256), 0, stream,
                     xT, Wbf, bq, bk, bv, Qt, Kt, Vt);
  hipLaunchKernelGGL(attn_kernel, dim3(512), dim3(256), 0, stream,
                     Qt, Kt, Vt, x, gamma, out);
}

// Round 7
// 94.537 us; speedup vs baseline: 1.8741x; 1.8741x over previous
//
#include <hip/hip_runtime.h>
#include <hip/hip_bf16.h>

#define NB 4
#define NC 256
#define NN 4096
#define NCR 32
#define PITCH 72   // shorts; 144B rows -> 2-way max aliasing (free per m136)

typedef __attribute__((ext_vector_type(8))) short short8_t;
typedef __attribute__((ext_vector_type(4))) float f32x4;
typedef __attribute__((ext_vector_type(2))) int int2_t;
typedef __attribute__((ext_vector_type(4))) int int4_t;
typedef __attribute__((ext_vector_type(4))) float float4_t;

static __device__ __forceinline__ unsigned short f2bf(float f) {
  unsigned u = __builtin_bit_cast(unsigned, f);
  u += 0x7FFFu + ((u >> 16) & 1u);
  return (unsigned short)(u >> 16);
}

static __device__ __forceinline__ unsigned cvt_pk(float lo, float hi) {
  unsigned r;
  asm("v_cvt_pk_bf16_f32 %0, %1, %2" : "=v"(r) : "v"(lo), "v"(hi));
  return r;
}

// LDS-only barrier: drains lgkmcnt (LDS ops) but leaves global loads in flight.
static __device__ __forceinline__ void lds_barrier() {
  asm volatile("s_waitcnt lgkmcnt(0)\n\ts_barrier" ::: "memory");
}

// ---------------------------------------------------------------------------
// Kernel 0: one-time W pack f32 -> bf16. rows [0,32)=Wq, [32,64)=Wk, [64,320)=Wv
// ---------------------------------------------------------------------------
__global__ __launch_bounds__(64) void pack_w_kernel(
    const float* __restrict__ Wq, const float* __restrict__ Wk,
    const float* __restrict__ Wv, unsigned short* __restrict__ Wbf)
{
  const int row = blockIdx.x;
  const int t = threadIdx.x;
  const float* src = row < 32 ? Wq + (size_t)row * NC
                   : (row < 64 ? Wk + (size_t)(row - 32) * NC
                               : Wv + (size_t)(row - 64) * NC);
  float4_t v = *(const float4_t*)(src + t * 4);
  int2_t p;
  p[0] = cvt_pk(v[0], v[1]);
  p[1] = cvt_pk(v[2], v[3]);
  *(int2_t*)(Wbf + (size_t)row * NC + t * 4) = p;
}

// ---------------------------------------------------------------------------
// Kernel 1: QKV projection (R3's fused version). BM=32, grid 512 =
// batch(4) x m-tile(128), 2 blocks/CU. x chunk (64k x 32m) staged in LDS bf16,
// XOR-swizzled. Swapped MFMA: D^T[m][d] so V stores are b64 along n.
// ---------------------------------------------------------------------------
__global__ __launch_bounds__(256, 2) void qkv_kernel(
    const float* __restrict__ x, const unsigned short* __restrict__ Wbf,
    const float* __restrict__ bq, const float* __restrict__ bk,
    const float* __restrict__ bv,
    unsigned short* __restrict__ Qt, unsigned short* __restrict__ Kt,
    unsigned short* __restrict__ Vt)
{
  __shared__ unsigned short xT[2][32 * 64];  // [buf][m][k-unit swizzled], 4KB

  const int bid = blockIdx.x;
  const int b   = bid >> 7;
  const int m0  = (bid & 127) * 32;
  const int tid = threadIdx.x;
  const int w    = tid >> 6;
  const int lane = tid & 63;
  const int lg   = lane >> 4;
  const int lm   = lane & 15;

  const int mcol = tid & 31, kg = tid >> 5;
  const float* xld = x + (size_t)b * NC * NN + (size_t)(kg * 8) * NN + m0 + mcol;
  const int wofs = mcol * 64 + ((kg ^ (mcol & 7)) << 3);
  const unsigned short* wrow = Wbf + (size_t)(w * 80 + lm) * NC;

  const f32x4 zero4 = {0.f, 0.f, 0.f, 0.f};
  f32x4 acc[5][2];
#pragma unroll
  for (int df = 0; df < 5; df++)
#pragma unroll
    for (int mf = 0; mf < 2; mf++) acc[df][mf] = zero4;

  float xg[8], xn[8];
#pragma unroll
  for (int j = 0; j < 8; j++) xg[j] = xld[(size_t)j * NN];

#define QCHUNK(C, XC, XN, BUF) {                                              \
    if ((C) < 3) {                                                            \
      _Pragma("unroll") for (int j = 0; j < 8; j++)                           \
        XN[j] = xld[(size_t)(((C) + 1) * 64 + j) * NN];                       \
    }                                                                         \
    int4_t xwv;                                                               \
    xwv[0] = cvt_pk(XC[0], XC[1]); xwv[1] = cvt_pk(XC[2], XC[3]);             \
    xwv[2] = cvt_pk(XC[4], XC[5]); xwv[3] = cvt_pk(XC[6], XC[7]);             \
    *(int4_t*)(&xT[BUF][wofs]) = xwv;                                         \
    __syncthreads();                                                          \
    _Pragma("unroll") for (int ks = 0; ks < 2; ks++) {                        \
      short8_t xf[2];                                                         \
      _Pragma("unroll") for (int mf = 0; mf < 2; mf++) {                      \
        const int row = mf * 16 + lm;                                         \
        const int unit = (ks * 4 + lg) ^ (lm & 7);                            \
        xf[mf] = *(const short8_t*)(&xT[BUF][row * 64 + unit * 8]);           \
      }                                                                       \
      _Pragma("unroll") for (int df = 0; df < 5; df++) {                      \
        const short8_t wf = *(const short8_t*)(wrow + (size_t)df * 16 * NC +  \
                                               (C) * 64 + ks * 32 + lg * 8);  \
        _Pragma("unroll") for (int mf = 0; mf < 2; mf++)                      \
          acc[df][mf] = __builtin_amdgcn_mfma_f32_16x16x32_bf16(              \
              xf[mf], wf, acc[df][mf], 0, 0, 0);                              \
      }                                                                       \
    }                                                                         \
  }

  QCHUNK(0, xg, xn, 0)
  QCHUNK(1, xn, xg, 1)
  QCHUNK(2, xg, xn, 0)
  QCHUNK(3, xn, xg, 1)
#undef QCHUNK

  // acc[df][mf][i] = D^T[m = m0+mf*16+4lg+i][d = w*80+df*16+lm]
#pragma unroll
  for (int df = 0; df < 5; df++) {
    const int dbase = w * 80 + df * 16;
    if (dbase < 64) {
      const bool isq = dbase < 32;
      const float bia = isq ? bq[dbase + lm] : bk[dbase - 32 + lm];
      unsigned short* dst = isq ? Qt : Kt;
      const int dcol = (isq ? dbase : dbase - 32) + lm;
#pragma unroll
      for (int mf = 0; mf < 2; mf++)
#pragma unroll
        for (int i = 0; i < 4; i++) {
          const int m = m0 + mf * 16 + lg * 4 + i;
          dst[((size_t)b * NN + m) * NCR + dcol] = f2bf(acc[df][mf][i] + bia);
        }
    } else {
      const int c = dbase - 64 + lm;
      const float bia = bv[c];
#pragma unroll
      for (int mf = 0; mf < 2; mf++) {
        int2_t p;
        p[0] = cvt_pk(acc[df][mf][0] + bia, acc[df][mf][1] + bia);
        p[1] = cvt_pk(acc[df][mf][2] + bia, acc[df][mf][3] + bia);
        *(int2_t*)(Vt + ((size_t)b * NC + c) * NN + m0 + mf * 16 + lg * 4) = p;
      }
    }
  }
}

// ---------------------------------------------------------------------------
// Kernel 2: streaming attention, SOFTWARE-PIPELINED one tile ahead:
// iteration t computes S[t+1] (into Slds[(t+1)&1]) while PV consumes S[t]
// (from Slds[t&1], written last iteration). PV never waits on work produced
// in its own iteration. One lgkm-only barrier per iteration.
// Grid 512 = batch x c-half x m-tile(64), 4 waves, 2 blocks/CU.
// ---------------------------------------------------------------------------
__global__ __launch_bounds__(256, 2) void attn_kernel(
    const unsigned short* __restrict__ Qt, const unsigned short* __restrict__ Kt,
    const unsigned short* __restrict__ Vt, const float* __restrict__ x,
    const float* __restrict__ gamma, float* __restrict__ out)
{
  __shared__ unsigned short Slds[2][64 * PITCH];  // 18.4 KB
  __shared__ float dlds[4][64];

  const int bid = blockIdx.x;
  const int xcd = bid & 7;
  const int b   = xcd >> 1;          // batch pinned to an XCD pair
  const int ch  = xcd & 1;           // c-half
  const int m0  = (bid >> 3) * 64;
  const int tid = threadIdx.x;
  const int w    = tid >> 6;
  const int lane = tid & 63;
  const int lg   = lane >> 4;
  const int lm   = lane & 15;

  const unsigned short* Qb = Qt + (size_t)b * NN * NCR;
  const unsigned short* Kp = Kt + (size_t)b * NN * NCR +
                             (size_t)(w * 16 + lm) * NCR + lg * 8;
  const unsigned short* pV[2];
#pragma unroll
  for (int cf = 0; cf < 2; cf++)
    pV[cf] = Vt + ((size_t)b * NC + ch * 128 + w * 32 + cf * 16 + lm) * NN + lg * 8;

  short8_t qf[4];
#pragma unroll
  for (int mf = 0; mf < 4; mf++)
    qf[mf] = *(const short8_t*)(Qb + (size_t)(m0 + mf * 16 + lm) * NCR + lg * 8);

  const f32x4 zero4 = {0.f, 0.f, 0.f, 0.f};
  f32x4 acc[2][4];
#pragma unroll
  for (int cf = 0; cf < 2; cf++)
#pragma unroll
    for (int mf = 0; mf < 4; mf++) acc[cf][mf] = zero4;
  float dsum[4] = {0.f, 0.f, 0.f, 0.f};

  const int swofs = w * 16 + lg * 4;

  // S-compute for tile index TT from K-frag KREG into LDS buffer WB
#define SCOMP(KREG, WB) {                                                     \
    _Pragma("unroll") for (int mf = 0; mf < 4; mf++) {                        \
      f32x4 s = __builtin_amdgcn_mfma_f32_16x16x32_bf16(KREG, qf[mf], zero4, 0, 0, 0); \
      float s0 = fmaxf(s[0], 0.f), s1 = fmaxf(s[1], 0.f);                     \
      float s2 = fmaxf(s[2], 0.f), s3 = fmaxf(s[3], 0.f);                     \
      dsum[mf] += (s0 + s1) + (s2 + s3);                                      \
      int2_t p; p[0] = cvt_pk(s0, s1); p[1] = cvt_pk(s2, s3);                 \
      *(int2_t*)(&Slds[WB][(mf * 16 + lm) * PITCH + swofs]) = p;              \
    }                                                                         \
  }

  // prologue: compute S[0] into buf0; preload K[1] and V[0]
  short8_t kA, kB, vA[2][2], vB[2][2];
  {
    const short8_t k0 = *(const short8_t*)(Kp);
    SCOMP(k0, 0)
  }
  kA = *(const short8_t*)(Kp + (size_t)64 * NCR);   // K[1]
#pragma unroll
  for (int cf = 0; cf < 2; cf++) {
    vA[cf][0] = *(const short8_t*)(pV[cf]);          // V[0]
    vA[cf][1] = *(const short8_t*)(pV[cf] + 32);
  }
  lds_barrier();

  // ITER(T): loads K[T+2], V[T+1]; computes S[T+1] -> Slds[WB];
  // PV consumes S[T] from Slds[RB] with V[T] (in VU). Barrier at end.
#define ITER(T, KU, KF, VU, VF, WB, RB, DOS) {                                \
    const int nk = (((T) + 2) & 63) * 64;                                     \
    KF = *(const short8_t*)(Kp + (size_t)nk * NCR);                           \
    const int nv = (((T) + 1) & 63) * 64;                                     \
    _Pragma("unroll") for (int cf = 0; cf < 2; cf++) {                        \
      VF[cf][0] = *(const short8_t*)(pV[cf] + nv);                            \
      VF[cf][1] = *(const short8_t*)(pV[cf] + nv + 32);                       \
    }                                                                         \
    if (DOS) { SCOMP(KU, WB) }                                                \
    __builtin_amdgcn_s_setprio(1);                                            \
    _Pragma("unroll") for (int nch = 0; nch < 2; nch++) {                     \
      short8_t sf[4];                                                         \
      _Pragma("unroll") for (int mf = 0; mf < 4; mf++)                        \
        sf[mf] = *(const short8_t*)(&Slds[RB][(mf * 16 + lm) * PITCH +        \
                                             nch * 32 + lg * 8]);             \
      _Pragma("unroll") for (int cf = 0; cf < 2; cf++)                        \
        _Pragma("unroll") for (int mf = 0; mf < 4; mf++)                      \
          acc[cf][mf] = __builtin_amdgcn_mfma_f32_16x16x32_bf16(              \
              VU[cf][nch], sf[mf], acc[cf][mf], 0, 0, 0);                     \
    }                                                                         \
    __builtin_amdgcn_s_setprio(0);                                            \
    lds_barrier();                                                            \
  }

#pragma unroll 1
  for (int t = 0; t < 62; t += 2) {
    ITER(t, kA, kB, vA, vB, 1, 0, true)
    ITER(t + 1, kB, kA, vB, vA, 0, 1, true)
  }
  ITER(62, kA, kB, vA, vB, 1, 0, true)
  ITER(63, kB, kA, vB, vA, 0, 1, false)
#undef ITER
#undef SCOMP

  // denominator: fold lane groups, then 4 waves via LDS
#pragma unroll
  for (int mf = 0; mf < 4; mf++) {
    float v = dsum[mf];
    v += __shfl_xor(v, 16);
    v += __shfl_xor(v, 32);
    if (lane < 16) dlds[w][mf * 16 + lane] = v;
  }
  __syncthreads();

  const float g0 = gamma[0];
  float rden[4];
#pragma unroll
  for (int mf = 0; mf < 4; mf++) {
    const int mloc = mf * 16 + lm;
    float den = dlds[0][mloc] + dlds[1][mloc] + dlds[2][mloc] + dlds[3][mloc];
    den = den > 1e-12f ? den : 1e-12f;
    rden[mf] = 1.0f / den;
  }

  const float* xb = x + (size_t)b * NC * NN;
  float* ob = out + (size_t)b * NC * NN;
#pragma unroll
  for (int cf = 0; cf < 2; cf++) {
#pragma unroll
    for (int i = 0; i < 4; i++) {
      const int c = ch * 128 + w * 32 + cf * 16 + lg * 4 + i;
#pragma unroll
      for (int mf = 0; mf < 4; mf++) {
        const int m = m0 + mf * 16 + lm;
        ob[(size_t)c * NN + m] = g0 * acc[cf][mf][i] * rden[mf] + xb[(size_t)c * NN + m];
      }
    }
  }
}

extern "C" void kernel_launch(void* const* d_in, const int* in_sizes, int n_in,
                              void* d_out, int out_size, void* d_ws, size_t ws_size,
                              hipStream_t stream) {
  const float* x     = (const float*)d_in[0];
  const float* Wq    = (const float*)d_in[1];
  const float* bq    = (const float*)d_in[2];
  const float* Wk    = (const float*)d_in[3];
  const float* bk    = (const float*)d_in[4];
  const float* Wv    = (const float*)d_in[5];
  const float* bv    = (const float*)d_in[6];
  const float* gamma = (const float*)d_in[7];
  float* out = (float*)d_out;

  // ws (bf16): Wbf[320][256], Qt[4][4096][32], Kt[4][4096][32], Vt[4][256][4096]
  unsigned short* Wbf = (unsigned short*)d_ws;
  unsigned short* Qt  = Wbf + (size_t)320 * NC;
  unsigned short* Kt  = Qt + (size_t)NB * NN * NCR;
  unsigned short* Vt  = Kt + (size_t)NB * NN * NCR;

  hipLaunchKernelGGL(pack_w_kernel, dim3(320), dim3(64), 0, stream,
                     Wq, Wk, Wv, Wbf);
  hipLaunchKernelGGL(qkv_kernel, dim3(512), dim3(256), 0, stream,
                     x, Wbf, bq, bk, bv, Qt, Kt, Vt);
  hipLaunchKernelGGL(attn_kernel, dim3(512), dim3(256), 0, stream,
                     Qt, Kt, Vt, x, gamma, out);
}